// Round 6
// baseline (1114.384 us; speedup 1.0000x reference)
//
#include <hip/hip_runtime.h>
#include <hip/hip_bf16.h>

// ---------------------------------------------------------------------------
// GCN forward: 3x { g = dinv.(act@W); act' = relu(dinv.(sum g[src] + g) + b) }
//              -> mean-pool(64) -> MLP(5)
// R4 (resubmit after acquisition timeout): k_count/k_fill keep the 8-chunk dst
// partition but stream src/dst with NON-TEMPORAL loads so the 25.6MB/pass edge
// streams never evict the chunk's write working set (col 1.6MB + cursor 100KB)
// from the XCD's 4MB L2.
// R3 post-mortem: spatial confinement alone didn't cut WRITE_SIZE (175MB) —
// dirty col lines stay open the whole kernel and get flushed by the read
// streams; the fix is keeping streams out of L2 (nt) + full occupancy.
// ---------------------------------------------------------------------------

#define CH 128
#define NCHUNK 8
#define BLKS_PER_CHUNK 256

static __device__ __forceinline__ unsigned short f2bf(float f) {
    unsigned u = __float_as_uint(f);
    u += 0x7fffu + ((u >> 16) & 1u);          // round-to-nearest-even
    return (unsigned short)(u >> 16);
}
static __device__ __forceinline__ float bf_lo(unsigned u) { return __uint_as_float(u << 16); }
static __device__ __forceinline__ float bf_hi(unsigned u) { return __uint_as_float(u & 0xffff0000u); }

// ---------------- degree count (dst-partitioned, nt streamed) ---------------
__global__ __launch_bounds__(256) void k_count(const int* __restrict__ dst, int e,
                                               int* __restrict__ cnt, int n) {
    int grp = blockIdx.x & (NCHUNK - 1);         // -> XCD grp (round-robin dispatch)
    int b2  = blockIdx.x >> 3;
    int chunk = (n + NCHUNK - 1) / NCHUNK;
    int lo = grp * chunk;
    int hi = lo + chunk; if (hi > n) hi = n;
    int stride = BLKS_PER_CHUNK * 256;
    for (int i = b2 * 256 + threadIdx.x; i < e; i += stride) {
        int d = __builtin_nontemporal_load(&dst[i]);   // stream: don't pollute L2
        if (d >= lo && d < hi) atomicAdd(&cnt[d], 1);
    }
}

// ---------------- hierarchical prefix scan (chunk=1024) ----------------
__global__ void k_scan_reduce(const int* __restrict__ cnt, int n, int* __restrict__ bsums) {
    __shared__ int sd[256];
    int b = blockIdx.x, t = threadIdx.x;
    int base = b * 1024;
    int s = 0;
    for (int i = t; i < 1024; i += 256) {
        int idx = base + i;
        if (idx < n) s += cnt[idx];
    }
    sd[t] = s; __syncthreads();
    for (int st = 128; st > 0; st >>= 1) {
        if (t < st) sd[t] += sd[t + st];
        __syncthreads();
    }
    if (t == 0) bsums[b] = sd[0];
}

__global__ void k_scan_bsums(const int* __restrict__ bsums, int nb, int* __restrict__ boffs) {
    __shared__ int sd[256];
    int t = threadIdx.x;
    int v = (t < nb) ? bsums[t] : 0;
    sd[t] = v; __syncthreads();
    for (int st = 1; st < 256; st <<= 1) {
        int x = (t >= st) ? sd[t - st] : 0;
        __syncthreads();
        sd[t] += x;
        __syncthreads();
    }
    if (t < nb) boffs[t] = sd[t] - v;   // exclusive
}

__global__ void k_scan_final(const int* __restrict__ cnt, int n,
                             const int* __restrict__ boffs, int* __restrict__ offs) {
    __shared__ int sd[256];
    int b = blockIdx.x, t = threadIdx.x;
    int base = b * 1024 + t * 4;
    int v[4]; int s = 0;
#pragma unroll
    for (int i = 0; i < 4; ++i) {
        int idx = base + i;
        v[i] = (idx < n) ? cnt[idx] : 0;
        s += v[i];
    }
    sd[t] = s; __syncthreads();
    for (int st = 1; st < 256; st <<= 1) {
        int x = (t >= st) ? sd[t - st] : 0;
        __syncthreads();
        sd[t] += x;
        __syncthreads();
    }
    int excl = sd[t] - s + boffs[b];
#pragma unroll
    for (int i = 0; i < 4; ++i) {
        int idx = base + i;
        if (idx < n) offs[idx] = excl;
        excl += v[i];
    }
}

// ---------------- norms + offs[n]=E ----------------
__global__ void k_norm(const int* __restrict__ cnt, int n,
                       float* __restrict__ dinv,
                       int* __restrict__ offs, int e) {
    int i = blockIdx.x * blockDim.x + threadIdx.x;
    if (i >= n) return;
    float d = (float)cnt[i] + 1.0f;
    dinv[i] = 1.0f / sqrtf(d);
    if (i == 0) offs[n] = e;
}

// ---------------- CSR fill (dst-partitioned, nt streamed) -------------------
__global__ __launch_bounds__(256) void k_fill(const int* __restrict__ src,
                                              const int* __restrict__ dst, int e,
                                              const int* __restrict__ offs,
                                              int* __restrict__ cursor,
                                              int* __restrict__ col, int n) {
    int grp = blockIdx.x & (NCHUNK - 1);
    int b2  = blockIdx.x >> 3;
    int chunk = (n + NCHUNK - 1) / NCHUNK;
    int lo = grp * chunk;
    int hi = lo + chunk; if (hi > n) hi = n;
    int stride = BLKS_PER_CHUNK * 256;
    for (int i = b2 * 256 + threadIdx.x; i < e; i += stride) {
        int d = __builtin_nontemporal_load(&dst[i]);   // stream
        if (d >= lo && d < hi) {
            int s = __builtin_nontemporal_load(&src[i]); // stream
            int pos = atomicAdd(&cursor[d], 1);          // hot: 50KB/chunk in L2
            col[offs[d] + pos] = s;                      // hot: 1.6MB/chunk in L2
        }
    }
}

// ---------------- GEMM: G[N,128](bf16) = dinv . (A[N,128] @ W[128,128]) -----
// 512 threads, 128 rows/block, W f32 in LDS (64KB -> 2 blocks/CU, 4 w/SIMD).
template <typename TA>
__global__ __launch_bounds__(512) void k_gemm(const TA* __restrict__ A,
                                              const float* __restrict__ W,
                                              const float* __restrict__ dinv,
                                              unsigned short* __restrict__ G, int n) {
    __shared__ float Ws[CH * CH];
    int t = threadIdx.x;
    for (int i = t * 4; i < CH * CH; i += 512 * 4)
        *(float4*)&Ws[i] = *(const float4*)&W[i];
    __syncthreads();

    int rowbase = blockIdx.x * 128;
    int cg = (t & 31) * 4;
    int rg = (t >> 5) * 8;
    float acc[8][4] = {{0.f}};

    for (int k4 = 0; k4 < 32; ++k4) {
        int k = k4 * 4;
        float4 w0 = *(float4*)&Ws[(k + 0) * CH + cg];
        float4 w1 = *(float4*)&Ws[(k + 1) * CH + cg];
        float4 w2 = *(float4*)&Ws[(k + 2) * CH + cg];
        float4 w3 = *(float4*)&Ws[(k + 3) * CH + cg];
#pragma unroll
        for (int j = 0; j < 8; ++j) {
            int row = rowbase + rg + j;
            int rr = row < n ? row : n - 1;           // clamp OOB reads
            float a0, a1, a2, a3;
            if constexpr (sizeof(TA) == 4) {
                float4 xv = *(const float4*)&((const float*)A)[(size_t)rr * CH + k];
                a0 = xv.x; a1 = xv.y; a2 = xv.z; a3 = xv.w;
            } else {
                uint2 uv = *(const uint2*)&((const unsigned short*)A)[(size_t)rr * CH + k];
                a0 = bf_lo(uv.x); a1 = bf_hi(uv.x);
                a2 = bf_lo(uv.y); a3 = bf_hi(uv.y);
            }
            acc[j][0] += a0 * w0.x + a1 * w1.x + a2 * w2.x + a3 * w3.x;
            acc[j][1] += a0 * w0.y + a1 * w1.y + a2 * w2.y + a3 * w3.y;
            acc[j][2] += a0 * w0.z + a1 * w1.z + a2 * w2.z + a3 * w3.z;
            acc[j][3] += a0 * w0.w + a1 * w1.w + a2 * w2.w + a3 * w3.w;
        }
    }
#pragma unroll
    for (int j = 0; j < 8; ++j) {
        int row = rowbase + rg + j;
        if (row < n) {
            float s = dinv[row];
            ushort4 o;
            o.x = f2bf(acc[j][0] * s);
            o.y = f2bf(acc[j][1] * s);
            o.z = f2bf(acc[j][2] * s);
            o.w = f2bf(acc[j][3] * s);
            *(ushort4*)&G[(size_t)row * CH + cg] = o;
        }
    }
}

// ---------------- aggregation: wave per node, lane = 2 bf16 channels --------
// act[i] = relu( dinv[i] * (sum_{src in N(i)} g[src] + g[i]) + b )   (bf16)
__global__ __launch_bounds__(256) void k_agg(const unsigned short* __restrict__ g,
                                             const int* __restrict__ offs,
                                             const int* __restrict__ col,
                                             const float* __restrict__ dinv,
                                             const float* __restrict__ bias,
                                             unsigned short* __restrict__ act, int n) {
    int node = (int)((blockIdx.x * (unsigned)blockDim.x + threadIdx.x) >> 6);
    int lane = threadIdx.x & 63;
    if (node >= n) return;
    int beg = offs[node], end = offs[node + 1];

    const unsigned* gp = (const unsigned*)g;   // one dword = 2 bf16 channels
    float ax = 0.f, ay = 0.f;

    for (int e0 = beg; e0 < end; e0 += 64) {
        int cnt = end - e0; if (cnt > 64) cnt = 64;
        int s_l = (lane < cnt) ? col[e0 + lane] : 0;
        int j = 0;
        for (; j + 4 <= cnt; j += 4) {
            int s0 = __shfl(s_l, j + 0);
            int s1 = __shfl(s_l, j + 1);
            int s2 = __shfl(s_l, j + 2);
            int s3 = __shfl(s_l, j + 3);
            unsigned u0 = gp[(size_t)s0 * 64 + lane];
            unsigned u1 = gp[(size_t)s1 * 64 + lane];
            unsigned u2 = gp[(size_t)s2 * 64 + lane];
            unsigned u3 = gp[(size_t)s3 * 64 + lane];
            ax += bf_lo(u0); ay += bf_hi(u0);
            ax += bf_lo(u1); ay += bf_hi(u1);
            ax += bf_lo(u2); ay += bf_hi(u2);
            ax += bf_lo(u3); ay += bf_hi(u3);
        }
        for (; j < cnt; ++j) {
            int s = __shfl(s_l, j);
            unsigned u = gp[(size_t)s * 64 + lane];
            ax += bf_lo(u); ay += bf_hi(u);
        }
    }

    unsigned us = gp[(size_t)node * 64 + lane];   // self-loop term
    ax += bf_lo(us); ay += bf_hi(us);

    float di = dinv[node];
    float2 b2 = ((const float2*)bias)[lane];
    float ox = fmaxf(ax * di + b2.x, 0.f);
    float oy = fmaxf(ay * di + b2.y, 0.f);
    unsigned o = (unsigned)f2bf(ox) | ((unsigned)f2bf(oy) << 16);
    ((unsigned*)act)[(size_t)node * 64 + lane] = o;
}

// ---------------- pooling: sorted batch ids, per-block running sums ---------
#define POOL_CHUNK 512
__global__ __launch_bounds__(128) void k_pool(const unsigned short* __restrict__ act,
                                              const int* __restrict__ batch, int n,
                                              float* __restrict__ sums, int* __restrict__ cnts) {
    int b = blockIdx.x, c = threadIdx.x;
    int beg = b * POOL_CHUNK;
    int end = beg + POOL_CHUNK; if (end > n) end = n;
    if (beg >= end) return;

    float acc = 0.f;
    int g = batch[beg];
    int cstart = beg;
    for (int i = beg; i < end; ++i) {
        int gi = batch[i];
        if (gi != g) {
            atomicAdd(&sums[g * CH + c], acc);
            if (c == 0) atomicAdd(&cnts[g], i - cstart);
            acc = 0.f; g = gi; cstart = i;
        }
        acc += __uint_as_float((unsigned)act[(size_t)i * CH + c] << 16);
    }
    atomicAdd(&sums[g * CH + c], acc);
    if (c == 0) atomicAdd(&cnts[g], end - cstart);
}

// ---------------- MLP head ----------------
__global__ __launch_bounds__(128) void k_mlp(const float* __restrict__ sums,
                                             const int* __restrict__ cnts,
                                             const float* __restrict__ Wm1,
                                             const float* __restrict__ bm1,
                                             const float* __restrict__ Wm2,
                                             const float* __restrict__ bm2,
                                             float* __restrict__ out) {
    int g = blockIdx.x, c = threadIdx.x;
    __shared__ float p[CH];
    __shared__ float hid[CH];
    float invc = 1.0f / fmaxf((float)cnts[g], 1.0f);
    p[c] = sums[g * CH + c] * invc;
    __syncthreads();
    float acc = bm1[c];
    for (int k = 0; k < CH; ++k) acc += p[k] * Wm1[k * CH + c];
    hid[c] = fmaxf(acc, 0.f);
    __syncthreads();
    if (c < 5) {
        float o = bm2[c];
        for (int k = 0; k < CH; ++k) o += hid[k] * Wm2[k * 5 + c];
        out[g * 5 + c] = o;
    }
}

// ---------------------------------------------------------------------------
extern "C" void kernel_launch(void* const* d_in, const int* in_sizes, int n_in,
                              void* d_out, int out_size, void* d_ws, size_t ws_size,
                              hipStream_t stream) {
    const float* x     = (const float*)d_in[0];
    const int*   ei    = (const int*)d_in[1];
    const int*   batch = (const int*)d_in[2];
    const float* W_in  = (const float*)d_in[3];
    const float* b_in  = (const float*)d_in[4];
    const float* W_hid = (const float*)d_in[5];
    const float* b_hid = (const float*)d_in[6];
    const float* Wm1   = (const float*)d_in[7];
    const float* bm1   = (const float*)d_in[8];
    const float* Wm2   = (const float*)d_in[9];
    const float* bm2   = (const float*)d_in[10];

    int n = in_sizes[0] / CH;       // 100000
    int e = in_sizes[1] / 2;        // 3200000
    const int* src = ei;
    const int* dst = ei + e;

    // workspace carve (256B aligned)
    char* p = (char*)d_ws;
    auto carve = [&](size_t bytes) {
        void* r = (void*)p;
        p += (bytes + 255) & ~(size_t)255;
        return r;
    };
    unsigned short* g   = (unsigned short*)carve((size_t)n * CH * 2);
    unsigned short* act = (unsigned short*)carve((size_t)n * CH * 2);
    int*   col    = (int*)  carve((size_t)e * 4);
    int*   cnt    = (int*)  carve((size_t)n * 4);
    int*   cursor = (int*)  carve((size_t)n * 4);
    int*   offs   = (int*)  carve((size_t)(n + 1) * 4);
    float* dinv   = (float*)carve((size_t)n * 4);
    int*   bsums  = (int*)  carve(256 * 4);
    int*   boffs  = (int*)  carve(256 * 4);
    float* sums   = (float*)carve(64 * CH * 4);
    int*   cnts   = (int*)  carve(64 * 4);

    hipMemsetAsync(cnt,    0, (size_t)n * 4, stream);
    hipMemsetAsync(cursor, 0, (size_t)n * 4, stream);
    hipMemsetAsync(sums,   0, 64 * CH * 4, stream);
    hipMemsetAsync(cnts,   0, 64 * 4, stream);

    int nb = (n + 1023) / 1024;
    k_count      <<<NCHUNK * BLKS_PER_CHUNK, 256, 0, stream>>>(dst, e, cnt, n);
    k_scan_reduce<<<nb, 256, 0, stream>>>(cnt, n, bsums);
    k_scan_bsums <<<1, 256, 0, stream>>>(bsums, nb, boffs);
    k_scan_final <<<nb, 256, 0, stream>>>(cnt, n, boffs, offs);
    k_norm       <<<(n + 255) / 256, 256, 0, stream>>>(cnt, n, dinv, offs, e);
    k_fill       <<<NCHUNK * BLKS_PER_CHUNK, 256, 0, stream>>>(src, dst, e, offs, cursor, col, n);

    dim3 ggemm((n + 127) / 128);
    dim3 gagg((n + 3) / 4);   // 4 waves per 256-thread block, wave per node

    // layer 1 (f32 input x)
    k_gemm<float>         <<<ggemm, 512, 0, stream>>>(x, W_in, dinv, g, n);
    k_agg                 <<<gagg, 256, 0, stream>>>(g, offs, col, dinv, b_in, act, n);
    // layer 2
    k_gemm<unsigned short><<<ggemm, 512, 0, stream>>>(act, W_hid, dinv, g, n);
    k_agg                 <<<gagg, 256, 0, stream>>>(g, offs, col, dinv, b_hid, act, n);
    // layer 3
    k_gemm<unsigned short><<<ggemm, 512, 0, stream>>>(act, W_hid + CH * CH, dinv, g, n);
    k_agg                 <<<gagg, 256, 0, stream>>>(g, offs, col, dinv, b_hid + CH, act, n);

    // pool + head
    k_pool<<<(n + POOL_CHUNK - 1) / POOL_CHUNK, 128, 0, stream>>>(act, batch, n, sums, cnts);
    k_mlp <<<64, 128, 0, stream>>>(sums, cnts, Wm1, bm1, Wm2, bm2, (float*)d_out);
}

// Round 7
// 1056.326 us; speedup vs baseline: 1.0550x; 1.0550x over previous
//
#include <hip/hip_runtime.h>
#include <hip/hip_bf16.h>

// ---------------------------------------------------------------------------
// GCN forward: 3x { g = dinv.(act@W); act' = relu(dinv.(sum g[src] + g) + b) }
//              -> mean-pool(64) -> MLP(5)
// R6: CSR build replaced by two-pass LDS-staged bucket sort.
//   kA_hist: per-bucket (dst>>7) histogram, LDS-local then padded global adds.
//   kA_scan: 782-entry scan -> bucket bases/cursors.
//   kB_scatter: append (ldst<<17|src) u32 to bucket tail (782 hot lines ->
//               dense, ~1x writeback; the R2-R5 counting-sort scatter hit
//               10-15x writeback amplification that cache hints couldn't fix).
//   kC_bucket: block per bucket; LDS count+scan -> dinv/offs (folds k_norm and
//              the 3 scan kernels), LDS scatter -> coalesced col flush.
// bdata aliases act (dead until agg1) -> no extra workspace.
// ---------------------------------------------------------------------------

#define CH 128
#define BSHIFT 7
#define BW 128            // bucket width = 1<<BSHIFT nodes
#define MAXB 6144         // staged-edge capacity per bucket (avg 4096, sigma 64)
#define HMAX 1024         // max buckets supported
#define CPAD 16           // cursor/hist padding (ints) -> one counter per line

static __device__ __forceinline__ unsigned short f2bf(float f) {
    unsigned u = __float_as_uint(f);
    u += 0x7fffu + ((u >> 16) & 1u);          // round-to-nearest-even
    return (unsigned short)(u >> 16);
}
static __device__ __forceinline__ float bf_lo(unsigned u) { return __uint_as_float(u << 16); }
static __device__ __forceinline__ float bf_hi(unsigned u) { return __uint_as_float(u & 0xffff0000u); }

// ---------------- pass A: bucket histogram ----------------
__global__ __launch_bounds__(256) void kA_hist(const int* __restrict__ dst, int e,
                                               int* __restrict__ hist, int nb) {
    __shared__ int lh[HMAX];
    for (int i = threadIdx.x; i < nb; i += 256) lh[i] = 0;
    __syncthreads();
    int stride = gridDim.x * 256;
    for (int i = blockIdx.x * 256 + threadIdx.x; i < e; i += stride) {
        int d = __builtin_nontemporal_load(&dst[i]);
        atomicAdd(&lh[d >> BSHIFT], 1);
    }
    __syncthreads();
    for (int i = threadIdx.x; i < nb; i += 256) {
        int v = lh[i];
        if (v) atomicAdd(&hist[i * CPAD], v);
    }
}

// ---------------- pass A2: scan bucket sizes -> bases + cursors ----------------
__global__ __launch_bounds__(1024) void kA_scan(const int* __restrict__ hist, int nb,
                                                int* __restrict__ bstart,
                                                int* __restrict__ cursor, int e) {
    __shared__ int sd[1024];
    int t = threadIdx.x;
    int v = (t < nb) ? hist[t * CPAD] : 0;
    sd[t] = v;
    __syncthreads();
    for (int st = 1; st < 1024; st <<= 1) {
        int x = (t >= st) ? sd[t - st] : 0;
        __syncthreads();
        sd[t] += x;
        __syncthreads();
    }
    if (t < nb) {
        int excl = sd[t] - v;
        bstart[t] = excl;
        cursor[t * CPAD] = excl;
    }
    if (t == 0) bstart[nb] = e;
}

// ---------------- pass B: scatter edges into dst-buckets ----------------
__global__ __launch_bounds__(256) void kB_scatter(const int* __restrict__ src,
                                                  const int* __restrict__ dst, int e,
                                                  int* __restrict__ cursor,
                                                  unsigned* __restrict__ bdata) {
    int stride = gridDim.x * 256;
    for (int i = blockIdx.x * 256 + threadIdx.x; i < e; i += stride) {
        int d = __builtin_nontemporal_load(&dst[i]);
        int s = __builtin_nontemporal_load(&src[i]);
        int b = d >> BSHIFT;
        int pos = atomicAdd(&cursor[b * CPAD], 1);
        bdata[pos] = ((unsigned)(d & (BW - 1)) << 17) | (unsigned)s;
    }
}

// ---------------- pass C: per-bucket counting sort in LDS ----------------
// Produces: dinv[node], offs[node] (CSR bases), col[] node-grouped src lists.
__global__ __launch_bounds__(256) void kC_bucket(const unsigned* __restrict__ bdata,
                                                 const int* __restrict__ bstart,
                                                 int n, int e,
                                                 int* __restrict__ offs,
                                                 float* __restrict__ dinv,
                                                 int* __restrict__ col) {
    __shared__ int cnt[BW];
    __shared__ int loff[BW];
    __shared__ unsigned est[MAXB];
    __shared__ int lcol[MAXB];
    int b = blockIdx.x, t = threadIdx.x;
    int bbase = bstart[b];
    int m = bstart[b + 1] - bbase;
    int lo = b << BSHIFT;
    bool staged = (m <= MAXB);

    if (t < BW) cnt[t] = 0;
    __syncthreads();
    if (staged) {
        for (int i = t; i < m; i += 256) {
            unsigned u = bdata[bbase + i];
            est[i] = u;
            atomicAdd(&cnt[u >> 17], 1);
        }
    } else {                                  // overflow fallback (never hit at these sizes)
        for (int i = t; i < m; i += 256)
            atomicAdd(&cnt[bdata[bbase + i] >> 17], 1);
    }
    __syncthreads();

    int cv = (t < BW) ? cnt[t] : 0;
    if (t < BW) loff[t] = cv;
    __syncthreads();
    for (int st = 1; st < BW; st <<= 1) {
        int x = 0;
        if (t < BW && t >= st) x = loff[t - st];
        __syncthreads();
        if (t < BW) loff[t] += x;
        __syncthreads();
    }
    if (t < BW) {
        int excl = loff[t] - cv;              // exclusive local offset
        loff[t] = excl;
        int node = lo + t;
        if (node < n) {
            float d = (float)cv + 1.0f;
            dinv[node] = 1.0f / sqrtf(d);
            offs[node] = bbase + excl;
        }
        cnt[t] = 0;                           // reuse as scatter cursor
    }
    if (b == 0 && t == 0) offs[n] = e;
    __syncthreads();

    if (staged) {
        for (int i = t; i < m; i += 256) {
            unsigned u = est[i];
            int ld = u >> 17;
            int pos = atomicAdd(&cnt[ld], 1);
            lcol[loff[ld] + pos] = (int)(u & 0x1FFFFu);
        }
        __syncthreads();
        for (int i = t; i < m; i += 256)      // coalesced flush
            col[bbase + i] = lcol[i];
    } else {
        for (int i = t; i < m; i += 256) {
            unsigned u = bdata[bbase + i];
            int ld = u >> 17;
            int pos = atomicAdd(&cnt[ld], 1);
            col[bbase + loff[ld] + pos] = (int)(u & 0x1FFFFu);
        }
    }
}

// ---------------- GEMM: G[N,128](bf16) = dinv . (A[N,128] @ W[128,128]) -----
// 512 threads, 128 rows/block, W f32 in LDS (64KB -> 2 blocks/CU, 4 w/SIMD).
template <typename TA>
__global__ __launch_bounds__(512) void k_gemm(const TA* __restrict__ A,
                                              const float* __restrict__ W,
                                              const float* __restrict__ dinv,
                                              unsigned short* __restrict__ G, int n) {
    __shared__ float Ws[CH * CH];
    int t = threadIdx.x;
    for (int i = t * 4; i < CH * CH; i += 512 * 4)
        *(float4*)&Ws[i] = *(const float4*)&W[i];
    __syncthreads();

    int rowbase = blockIdx.x * 128;
    int cg = (t & 31) * 4;
    int rg = (t >> 5) * 8;
    float acc[8][4] = {{0.f}};

    for (int k4 = 0; k4 < 32; ++k4) {
        int k = k4 * 4;
        float4 w0 = *(float4*)&Ws[(k + 0) * CH + cg];
        float4 w1 = *(float4*)&Ws[(k + 1) * CH + cg];
        float4 w2 = *(float4*)&Ws[(k + 2) * CH + cg];
        float4 w3 = *(float4*)&Ws[(k + 3) * CH + cg];
#pragma unroll
        for (int j = 0; j < 8; ++j) {
            int row = rowbase + rg + j;
            int rr = row < n ? row : n - 1;           // clamp OOB reads
            float a0, a1, a2, a3;
            if constexpr (sizeof(TA) == 4) {
                float4 xv = *(const float4*)&((const float*)A)[(size_t)rr * CH + k];
                a0 = xv.x; a1 = xv.y; a2 = xv.z; a3 = xv.w;
            } else {
                uint2 uv = *(const uint2*)&((const unsigned short*)A)[(size_t)rr * CH + k];
                a0 = bf_lo(uv.x); a1 = bf_hi(uv.x);
                a2 = bf_lo(uv.y); a3 = bf_hi(uv.y);
            }
            acc[j][0] += a0 * w0.x + a1 * w1.x + a2 * w2.x + a3 * w3.x;
            acc[j][1] += a0 * w0.y + a1 * w1.y + a2 * w2.y + a3 * w3.y;
            acc[j][2] += a0 * w0.z + a1 * w1.z + a2 * w2.z + a3 * w3.z;
            acc[j][3] += a0 * w0.w + a1 * w1.w + a2 * w2.w + a3 * w3.w;
        }
    }
#pragma unroll
    for (int j = 0; j < 8; ++j) {
        int row = rowbase + rg + j;
        if (row < n) {
            float s = dinv[row];
            ushort4 o;
            o.x = f2bf(acc[j][0] * s);
            o.y = f2bf(acc[j][1] * s);
            o.z = f2bf(acc[j][2] * s);
            o.w = f2bf(acc[j][3] * s);
            *(ushort4*)&G[(size_t)row * CH + cg] = o;
        }
    }
}

// ---------------- aggregation: wave per node, lane = 2 bf16 channels --------
// act[i] = relu( dinv[i] * (sum_{src in N(i)} g[src] + g[i]) + b )   (bf16)
__global__ __launch_bounds__(256) void k_agg(const unsigned short* __restrict__ g,
                                             const int* __restrict__ offs,
                                             const int* __restrict__ col,
                                             const float* __restrict__ dinv,
                                             const float* __restrict__ bias,
                                             unsigned short* __restrict__ act, int n) {
    int node = (int)((blockIdx.x * (unsigned)blockDim.x + threadIdx.x) >> 6);
    int lane = threadIdx.x & 63;
    if (node >= n) return;
    int beg = offs[node], end = offs[node + 1];

    const unsigned* gp = (const unsigned*)g;   // one dword = 2 bf16 channels
    float ax = 0.f, ay = 0.f;

    for (int e0 = beg; e0 < end; e0 += 64) {
        int cnt = end - e0; if (cnt > 64) cnt = 64;
        int s_l = (lane < cnt) ? col[e0 + lane] : 0;
        int j = 0;
        for (; j + 4 <= cnt; j += 4) {
            int s0 = __shfl(s_l, j + 0);
            int s1 = __shfl(s_l, j + 1);
            int s2 = __shfl(s_l, j + 2);
            int s3 = __shfl(s_l, j + 3);
            unsigned u0 = gp[(size_t)s0 * 64 + lane];
            unsigned u1 = gp[(size_t)s1 * 64 + lane];
            unsigned u2 = gp[(size_t)s2 * 64 + lane];
            unsigned u3 = gp[(size_t)s3 * 64 + lane];
            ax += bf_lo(u0); ay += bf_hi(u0);
            ax += bf_lo(u1); ay += bf_hi(u1);
            ax += bf_lo(u2); ay += bf_hi(u2);
            ax += bf_lo(u3); ay += bf_hi(u3);
        }
        for (; j < cnt; ++j) {
            int s = __shfl(s_l, j);
            unsigned u = gp[(size_t)s * 64 + lane];
            ax += bf_lo(u); ay += bf_hi(u);
        }
    }

    unsigned us = gp[(size_t)node * 64 + lane];   // self-loop term
    ax += bf_lo(us); ay += bf_hi(us);

    float di = dinv[node];
    float2 b2 = ((const float2*)bias)[lane];
    float ox = fmaxf(ax * di + b2.x, 0.f);
    float oy = fmaxf(ay * di + b2.y, 0.f);
    unsigned o = (unsigned)f2bf(ox) | ((unsigned)f2bf(oy) << 16);
    ((unsigned*)act)[(size_t)node * 64 + lane] = o;
}

// ---------------- pooling: sorted batch ids, per-block running sums ---------
#define POOL_CHUNK 512
__global__ __launch_bounds__(128) void k_pool(const unsigned short* __restrict__ act,
                                              const int* __restrict__ batch, int n,
                                              float* __restrict__ sums, int* __restrict__ cnts) {
    int b = blockIdx.x, c = threadIdx.x;
    int beg = b * POOL_CHUNK;
    int end = beg + POOL_CHUNK; if (end > n) end = n;
    if (beg >= end) return;

    float acc = 0.f;
    int g = batch[beg];
    int cstart = beg;
    for (int i = beg; i < end; ++i) {
        int gi = batch[i];
        if (gi != g) {
            atomicAdd(&sums[g * CH + c], acc);
            if (c == 0) atomicAdd(&cnts[g], i - cstart);
            acc = 0.f; g = gi; cstart = i;
        }
        acc += __uint_as_float((unsigned)act[(size_t)i * CH + c] << 16);
    }
    atomicAdd(&sums[g * CH + c], acc);
    if (c == 0) atomicAdd(&cnts[g], end - cstart);
}

// ---------------- MLP head ----------------
__global__ __launch_bounds__(128) void k_mlp(const float* __restrict__ sums,
                                             const int* __restrict__ cnts,
                                             const float* __restrict__ Wm1,
                                             const float* __restrict__ bm1,
                                             const float* __restrict__ Wm2,
                                             const float* __restrict__ bm2,
                                             float* __restrict__ out) {
    int g = blockIdx.x, c = threadIdx.x;
    __shared__ float p[CH];
    __shared__ float hid[CH];
    float invc = 1.0f / fmaxf((float)cnts[g], 1.0f);
    p[c] = sums[g * CH + c] * invc;
    __syncthreads();
    float acc = bm1[c];
    for (int k = 0; k < CH; ++k) acc += p[k] * Wm1[k * CH + c];
    hid[c] = fmaxf(acc, 0.f);
    __syncthreads();
    if (c < 5) {
        float o = bm2[c];
        for (int k = 0; k < CH; ++k) o += hid[k] * Wm2[k * 5 + c];
        out[g * 5 + c] = o;
    }
}

// ---------------------------------------------------------------------------
extern "C" void kernel_launch(void* const* d_in, const int* in_sizes, int n_in,
                              void* d_out, int out_size, void* d_ws, size_t ws_size,
                              hipStream_t stream) {
    const float* x     = (const float*)d_in[0];
    const int*   ei    = (const int*)d_in[1];
    const int*   batch = (const int*)d_in[2];
    const float* W_in  = (const float*)d_in[3];
    const float* b_in  = (const float*)d_in[4];
    const float* W_hid = (const float*)d_in[5];
    const float* b_hid = (const float*)d_in[6];
    const float* Wm1   = (const float*)d_in[7];
    const float* bm1   = (const float*)d_in[8];
    const float* Wm2   = (const float*)d_in[9];
    const float* bm2   = (const float*)d_in[10];

    int n = in_sizes[0] / CH;       // 100000
    int e = in_sizes[1] / 2;        // 3200000
    const int* src = ei;
    const int* dst = ei + e;
    int nb = (n + BW - 1) >> BSHIFT;   // 782 buckets

    // workspace carve (256B aligned)
    char* p = (char*)d_ws;
    auto carve = [&](size_t bytes) {
        void* r = (void*)p;
        p += (bytes + 255) & ~(size_t)255;
        return r;
    };
    unsigned short* g   = (unsigned short*)carve((size_t)n * CH * 2);
    unsigned short* act = (unsigned short*)carve((size_t)n * CH * 2);
    int*   col    = (int*)  carve((size_t)e * 4);
    int*   offs   = (int*)  carve((size_t)(n + 1) * 4);
    float* dinv   = (float*)carve((size_t)n * 4);
    int*   hist   = (int*)  carve((size_t)HMAX * CPAD * 4);
    int*   cursor = (int*)  carve((size_t)HMAX * CPAD * 4);
    int*   bstart = (int*)  carve((size_t)(HMAX + 1) * 4);
    float* sums   = (float*)carve(64 * CH * 4);
    int*   cnts   = (int*)  carve(64 * 4);

    // bdata (e u32 = 12.8MB) aliases act (25.6MB): dead until agg1 writes act.
    unsigned* bdata = (unsigned*)act;

    hipMemsetAsync(hist, 0, (size_t)HMAX * CPAD * 4, stream);
    hipMemsetAsync(sums, 0, 64 * CH * 4, stream);
    hipMemsetAsync(cnts, 0, 64 * 4, stream);

    kA_hist   <<<1024, 256, 0, stream>>>(dst, e, hist, nb);
    kA_scan   <<<1, 1024, 0, stream>>>(hist, nb, bstart, cursor, e);
    kB_scatter<<<2048, 256, 0, stream>>>(src, dst, e, cursor, bdata);
    kC_bucket <<<nb, 256, 0, stream>>>(bdata, bstart, n, e, offs, dinv, col);

    dim3 ggemm((n + 127) / 128);
    dim3 gagg((n + 3) / 4);   // 4 waves per 256-thread block, wave per node

    // layer 1 (f32 input x)
    k_gemm<float>         <<<ggemm, 512, 0, stream>>>(x, W_in, dinv, g, n);
    k_agg                 <<<gagg, 256, 0, stream>>>(g, offs, col, dinv, b_in, act, n);
    // layer 2
    k_gemm<unsigned short><<<ggemm, 512, 0, stream>>>(act, W_hid, dinv, g, n);
    k_agg                 <<<gagg, 256, 0, stream>>>(g, offs, col, dinv, b_hid, act, n);
    // layer 3
    k_gemm<unsigned short><<<ggemm, 512, 0, stream>>>(act, W_hid + CH * CH, dinv, g, n);
    k_agg                 <<<gagg, 256, 0, stream>>>(g, offs, col, dinv, b_hid + CH, act, n);

    // pool + head
    k_pool<<<(n + POOL_CHUNK - 1) / POOL_CHUNK, 128, 0, stream>>>(act, batch, n, sums, cnts);
    k_mlp <<<64, 128, 0, stream>>>(sums, cnts, Wm1, bm1, Wm2, bm2, (float*)d_out);
}

// Round 8
// 1036.088 us; speedup vs baseline: 1.0756x; 1.0195x over previous
//
#include <hip/hip_runtime.h>
#include <hip/hip_bf16.h>

// ---------------------------------------------------------------------------
// GCN forward: 3x { g = dinv.(act@W); act' = relu(dinv.(sum g[src] + g) + b) }
//              -> mean-pool(64) -> MLP(5)
// R7: XCD-segmented bucket tails. R6 post-mortem: kB_scatter WRITE_SIZE=167MB
// (= E x 52B, ~every 4B append flushed a 64B line) because the global cursor
// interleaves appends to each bucket tail across all 8 XCDs -> dirty-line
// ping-pong, each migration a writeback. Fix: 8 sub-segments per bucket, one
// per block-group (blockIdx&7 ~ XCD); a tail line is then written by only one
// XCD and stays in its L2 until full. Bucket-major layout keeps each bucket's
// edges contiguous, so kC_bucket is unchanged.
// ---------------------------------------------------------------------------

#define CH 128
#define BSHIFT 7
#define BW 128            // bucket width = 1<<BSHIFT nodes
#define MAXB 6144         // staged-edge capacity per bucket (avg 4092)
#define HMAX 1024         // max buckets supported
#define NSEG 8            // per-bucket segments (one per XCD group)
#define CPAD 16           // cursor padding (ints) -> one counter per 64B line
#define KB_GRID 2048      // kA_hist and kB_scatter MUST share this grid

static __device__ __forceinline__ unsigned short f2bf(float f) {
    unsigned u = __float_as_uint(f);
    u += 0x7fffu + ((u >> 16) & 1u);          // round-to-nearest-even
    return (unsigned short)(u >> 16);
}
static __device__ __forceinline__ float bf_lo(unsigned u) { return __uint_as_float(u << 16); }
static __device__ __forceinline__ float bf_hi(unsigned u) { return __uint_as_float(u & 0xffff0000u); }

// ---------------- pass A: per-(bucket, group) histogram ----------------
// Same edge->block decomposition as kB_scatter so counts match per (b,g).
__global__ __launch_bounds__(256) void kA_hist(const int* __restrict__ dst, int e,
                                               int* __restrict__ hist, int nb) {
    __shared__ int lh[HMAX];
    for (int i = threadIdx.x; i < nb; i += 256) lh[i] = 0;
    __syncthreads();
    int grp = blockIdx.x & (NSEG - 1);
    int stride = KB_GRID * 256;
    for (int i = blockIdx.x * 256 + threadIdx.x; i < e; i += stride) {
        int d = __builtin_nontemporal_load(&dst[i]);
        atomicAdd(&lh[d >> BSHIFT], 1);
    }
    __syncthreads();
    for (int i = threadIdx.x; i < nb; i += 256) {
        int v = lh[i];
        if (v) atomicAdd(&hist[i * NSEG + grp], v);
    }
}

// ---------------- pass A2: scan (bucket-major, per-seg cursors) -------------
__global__ __launch_bounds__(1024) void kA_scan(const int* __restrict__ hist, int nb,
                                                int* __restrict__ bstart,
                                                int* __restrict__ cursor, int e) {
    __shared__ int sd[1024];
    int t = threadIdx.x;
    int hv[NSEG];
    int v = 0;
    if (t < nb) {
#pragma unroll
        for (int g = 0; g < NSEG; ++g) { hv[g] = hist[t * NSEG + g]; v += hv[g]; }
    }
    sd[t] = v;
    __syncthreads();
    for (int st = 1; st < 1024; st <<= 1) {
        int x = (t >= st) ? sd[t - st] : 0;
        __syncthreads();
        sd[t] += x;
        __syncthreads();
    }
    if (t < nb) {
        int run = sd[t] - v;                  // bucket-exclusive prefix
        bstart[t] = run;
#pragma unroll
        for (int g = 0; g < NSEG; ++g) {
            cursor[(t * NSEG + g) * CPAD] = run;
            run += hv[g];
        }
    }
    if (t == 0) bstart[nb] = e;
}

// ---------------- pass B: scatter edges into per-(bucket,group) segments ----
__global__ __launch_bounds__(256) void kB_scatter(const int* __restrict__ src,
                                                  const int* __restrict__ dst, int e,
                                                  int* __restrict__ cursor,
                                                  unsigned* __restrict__ bdata) {
    int grp = blockIdx.x & (NSEG - 1);
    int stride = KB_GRID * 256;
    for (int i = blockIdx.x * 256 + threadIdx.x; i < e; i += stride) {
        int d = __builtin_nontemporal_load(&dst[i]);
        int s = __builtin_nontemporal_load(&src[i]);
        int b = d >> BSHIFT;
        int pos = atomicAdd(&cursor[(b * NSEG + grp) * CPAD], 1);
        bdata[pos] = ((unsigned)(d & (BW - 1)) << 17) | (unsigned)s;
    }
}

// ---------------- pass C: per-bucket counting sort in LDS ----------------
// Produces: dinv[node], offs[node] (CSR bases), col[] node-grouped src lists.
__global__ __launch_bounds__(256) void kC_bucket(const unsigned* __restrict__ bdata,
                                                 const int* __restrict__ bstart,
                                                 int n, int e,
                                                 int* __restrict__ offs,
                                                 float* __restrict__ dinv,
                                                 int* __restrict__ col) {
    __shared__ int cnt[BW];
    __shared__ int loff[BW];
    __shared__ unsigned est[MAXB];
    __shared__ int lcol[MAXB];
    int b = blockIdx.x, t = threadIdx.x;
    int bbase = bstart[b];
    int m = bstart[b + 1] - bbase;
    int lo = b << BSHIFT;
    bool staged = (m <= MAXB);

    if (t < BW) cnt[t] = 0;
    __syncthreads();
    if (staged) {
        for (int i = t; i < m; i += 256) {
            unsigned u = bdata[bbase + i];
            est[i] = u;
            atomicAdd(&cnt[u >> 17], 1);
        }
    } else {                                  // overflow fallback (never hit at these sizes)
        for (int i = t; i < m; i += 256)
            atomicAdd(&cnt[bdata[bbase + i] >> 17], 1);
    }
    __syncthreads();

    int cv = (t < BW) ? cnt[t] : 0;
    if (t < BW) loff[t] = cv;
    __syncthreads();
    for (int st = 1; st < BW; st <<= 1) {
        int x = 0;
        if (t < BW && t >= st) x = loff[t - st];
        __syncthreads();
        if (t < BW) loff[t] += x;
        __syncthreads();
    }
    if (t < BW) {
        int excl = loff[t] - cv;              // exclusive local offset
        loff[t] = excl;
        int node = lo + t;
        if (node < n) {
            float d = (float)cv + 1.0f;
            dinv[node] = 1.0f / sqrtf(d);
            offs[node] = bbase + excl;
        }
        cnt[t] = 0;                           // reuse as scatter cursor
    }
    if (b == 0 && t == 0) offs[n] = e;
    __syncthreads();

    if (staged) {
        for (int i = t; i < m; i += 256) {
            unsigned u = est[i];
            int ld = u >> 17;
            int pos = atomicAdd(&cnt[ld], 1);
            lcol[loff[ld] + pos] = (int)(u & 0x1FFFFu);
        }
        __syncthreads();
        for (int i = t; i < m; i += 256)      // coalesced flush
            col[bbase + i] = lcol[i];
    } else {
        for (int i = t; i < m; i += 256) {
            unsigned u = bdata[bbase + i];
            int ld = u >> 17;
            int pos = atomicAdd(&cnt[ld], 1);
            col[bbase + loff[ld] + pos] = (int)(u & 0x1FFFFu);
        }
    }
}

// ---------------- GEMM: G[N,128](bf16) = dinv . (A[N,128] @ W[128,128]) -----
// 512 threads, 128 rows/block, W f32 in LDS (64KB -> 2 blocks/CU, 4 w/SIMD).
template <typename TA>
__global__ __launch_bounds__(512) void k_gemm(const TA* __restrict__ A,
                                              const float* __restrict__ W,
                                              const float* __restrict__ dinv,
                                              unsigned short* __restrict__ G, int n) {
    __shared__ float Ws[CH * CH];
    int t = threadIdx.x;
    for (int i = t * 4; i < CH * CH; i += 512 * 4)
        *(float4*)&Ws[i] = *(const float4*)&W[i];
    __syncthreads();

    int rowbase = blockIdx.x * 128;
    int cg = (t & 31) * 4;
    int rg = (t >> 5) * 8;
    float acc[8][4] = {{0.f}};

    for (int k4 = 0; k4 < 32; ++k4) {
        int k = k4 * 4;
        float4 w0 = *(float4*)&Ws[(k + 0) * CH + cg];
        float4 w1 = *(float4*)&Ws[(k + 1) * CH + cg];
        float4 w2 = *(float4*)&Ws[(k + 2) * CH + cg];
        float4 w3 = *(float4*)&Ws[(k + 3) * CH + cg];
#pragma unroll
        for (int j = 0; j < 8; ++j) {
            int row = rowbase + rg + j;
            int rr = row < n ? row : n - 1;           // clamp OOB reads
            float a0, a1, a2, a3;
            if constexpr (sizeof(TA) == 4) {
                float4 xv = *(const float4*)&((const float*)A)[(size_t)rr * CH + k];
                a0 = xv.x; a1 = xv.y; a2 = xv.z; a3 = xv.w;
            } else {
                uint2 uv = *(const uint2*)&((const unsigned short*)A)[(size_t)rr * CH + k];
                a0 = bf_lo(uv.x); a1 = bf_hi(uv.x);
                a2 = bf_lo(uv.y); a3 = bf_hi(uv.y);
            }
            acc[j][0] += a0 * w0.x + a1 * w1.x + a2 * w2.x + a3 * w3.x;
            acc[j][1] += a0 * w0.y + a1 * w1.y + a2 * w2.y + a3 * w3.y;
            acc[j][2] += a0 * w0.z + a1 * w1.z + a2 * w2.z + a3 * w3.z;
            acc[j][3] += a0 * w0.w + a1 * w1.w + a2 * w2.w + a3 * w3.w;
        }
    }
#pragma unroll
    for (int j = 0; j < 8; ++j) {
        int row = rowbase + rg + j;
        if (row < n) {
            float s = dinv[row];
            ushort4 o;
            o.x = f2bf(acc[j][0] * s);
            o.y = f2bf(acc[j][1] * s);
            o.z = f2bf(acc[j][2] * s);
            o.w = f2bf(acc[j][3] * s);
            *(ushort4*)&G[(size_t)row * CH + cg] = o;
        }
    }
}

// ---------------- aggregation: wave per node, lane = 2 bf16 channels --------
// act[i] = relu( dinv[i] * (sum_{src in N(i)} g[src] + g[i]) + b )   (bf16)
__global__ __launch_bounds__(256) void k_agg(const unsigned short* __restrict__ g,
                                             const int* __restrict__ offs,
                                             const int* __restrict__ col,
                                             const float* __restrict__ dinv,
                                             const float* __restrict__ bias,
                                             unsigned short* __restrict__ act, int n) {
    int node = (int)((blockIdx.x * (unsigned)blockDim.x + threadIdx.x) >> 6);
    int lane = threadIdx.x & 63;
    if (node >= n) return;
    int beg = offs[node], end = offs[node + 1];

    const unsigned* gp = (const unsigned*)g;   // one dword = 2 bf16 channels
    float ax = 0.f, ay = 0.f;

    for (int e0 = beg; e0 < end; e0 += 64) {
        int cnt = end - e0; if (cnt > 64) cnt = 64;
        int s_l = (lane < cnt) ? col[e0 + lane] : 0;
        int j = 0;
        for (; j + 4 <= cnt; j += 4) {
            int s0 = __shfl(s_l, j + 0);
            int s1 = __shfl(s_l, j + 1);
            int s2 = __shfl(s_l, j + 2);
            int s3 = __shfl(s_l, j + 3);
            unsigned u0 = gp[(size_t)s0 * 64 + lane];
            unsigned u1 = gp[(size_t)s1 * 64 + lane];
            unsigned u2 = gp[(size_t)s2 * 64 + lane];
            unsigned u3 = gp[(size_t)s3 * 64 + lane];
            ax += bf_lo(u0); ay += bf_hi(u0);
            ax += bf_lo(u1); ay += bf_hi(u1);
            ax += bf_lo(u2); ay += bf_hi(u2);
            ax += bf_lo(u3); ay += bf_hi(u3);
        }
        for (; j < cnt; ++j) {
            int s = __shfl(s_l, j);
            unsigned u = gp[(size_t)s * 64 + lane];
            ax += bf_lo(u); ay += bf_hi(u);
        }
    }

    unsigned us = gp[(size_t)node * 64 + lane];   // self-loop term
    ax += bf_lo(us); ay += bf_hi(us);

    float di = dinv[node];
    float2 b2 = ((const float2*)bias)[lane];
    float ox = fmaxf(ax * di + b2.x, 0.f);
    float oy = fmaxf(ay * di + b2.y, 0.f);
    unsigned o = (unsigned)f2bf(ox) | ((unsigned)f2bf(oy) << 16);
    ((unsigned*)act)[(size_t)node * 64 + lane] = o;
}

// ---------------- pooling: sorted batch ids, per-block running sums ---------
#define POOL_CHUNK 512
__global__ __launch_bounds__(128) void k_pool(const unsigned short* __restrict__ act,
                                              const int* __restrict__ batch, int n,
                                              float* __restrict__ sums, int* __restrict__ cnts) {
    int b = blockIdx.x, c = threadIdx.x;
    int beg = b * POOL_CHUNK;
    int end = beg + POOL_CHUNK; if (end > n) end = n;
    if (beg >= end) return;

    float acc = 0.f;
    int g = batch[beg];
    int cstart = beg;
    for (int i = beg; i < end; ++i) {
        int gi = batch[i];
        if (gi != g) {
            atomicAdd(&sums[g * CH + c], acc);
            if (c == 0) atomicAdd(&cnts[g], i - cstart);
            acc = 0.f; g = gi; cstart = i;
        }
        acc += __uint_as_float((unsigned)act[(size_t)i * CH + c] << 16);
    }
    atomicAdd(&sums[g * CH + c], acc);
    if (c == 0) atomicAdd(&cnts[g], end - cstart);
}

// ---------------- MLP head ----------------
__global__ __launch_bounds__(128) void k_mlp(const float* __restrict__ sums,
                                             const int* __restrict__ cnts,
                                             const float* __restrict__ Wm1,
                                             const float* __restrict__ bm1,
                                             const float* __restrict__ Wm2,
                                             const float* __restrict__ bm2,
                                             float* __restrict__ out) {
    int g = blockIdx.x, c = threadIdx.x;
    __shared__ float p[CH];
    __shared__ float hid[CH];
    float invc = 1.0f / fmaxf((float)cnts[g], 1.0f);
    p[c] = sums[g * CH + c] * invc;
    __syncthreads();
    float acc = bm1[c];
    for (int k = 0; k < CH; ++k) acc += p[k] * Wm1[k * CH + c];
    hid[c] = fmaxf(acc, 0.f);
    __syncthreads();
    if (c < 5) {
        float o = bm2[c];
        for (int k = 0; k < CH; ++k) o += hid[k] * Wm2[k * 5 + c];
        out[g * 5 + c] = o;
    }
}

// ---------------------------------------------------------------------------
extern "C" void kernel_launch(void* const* d_in, const int* in_sizes, int n_in,
                              void* d_out, int out_size, void* d_ws, size_t ws_size,
                              hipStream_t stream) {
    const float* x     = (const float*)d_in[0];
    const int*   ei    = (const int*)d_in[1];
    const int*   batch = (const int*)d_in[2];
    const float* W_in  = (const float*)d_in[3];
    const float* b_in  = (const float*)d_in[4];
    const float* W_hid = (const float*)d_in[5];
    const float* b_hid = (const float*)d_in[6];
    const float* Wm1   = (const float*)d_in[7];
    const float* bm1   = (const float*)d_in[8];
    const float* Wm2   = (const float*)d_in[9];
    const float* bm2   = (const float*)d_in[10];

    int n = in_sizes[0] / CH;       // 100000
    int e = in_sizes[1] / 2;        // 3200000
    const int* src = ei;
    const int* dst = ei + e;
    int nb = (n + BW - 1) >> BSHIFT;   // 782 buckets

    // workspace carve (256B aligned)
    char* p = (char*)d_ws;
    auto carve = [&](size_t bytes) {
        void* r = (void*)p;
        p += (bytes + 255) & ~(size_t)255;
        return r;
    };
    unsigned short* g   = (unsigned short*)carve((size_t)n * CH * 2);
    unsigned short* act = (unsigned short*)carve((size_t)n * CH * 2);
    int*   col    = (int*)  carve((size_t)e * 4);
    int*   offs   = (int*)  carve((size_t)(n + 1) * 4);
    float* dinv   = (float*)carve((size_t)n * 4);
    int*   hist   = (int*)  carve((size_t)HMAX * NSEG * 4);
    int*   cursor = (int*)  carve((size_t)HMAX * NSEG * CPAD * 4);
    int*   bstart = (int*)  carve((size_t)(HMAX + 1) * 4);
    float* sums   = (float*)carve(64 * CH * 4);
    int*   cnts   = (int*)  carve(64 * 4);

    // bdata (e u32 = 12.8MB) aliases act (25.6MB): dead until agg1 writes act.
    unsigned* bdata = (unsigned*)act;

    hipMemsetAsync(hist, 0, (size_t)HMAX * NSEG * 4, stream);
    hipMemsetAsync(sums, 0, 64 * CH * 4, stream);
    hipMemsetAsync(cnts, 0, 64 * 4, stream);

    kA_hist   <<<KB_GRID, 256, 0, stream>>>(dst, e, hist, nb);
    kA_scan   <<<1, 1024, 0, stream>>>(hist, nb, bstart, cursor, e);
    kB_scatter<<<KB_GRID, 256, 0, stream>>>(src, dst, e, cursor, bdata);
    kC_bucket <<<nb, 256, 0, stream>>>(bdata, bstart, n, e, offs, dinv, col);

    dim3 ggemm((n + 127) / 128);
    dim3 gagg((n + 3) / 4);   // 4 waves per 256-thread block, wave per node

    // layer 1 (f32 input x)
    k_gemm<float>         <<<ggemm, 512, 0, stream>>>(x, W_in, dinv, g, n);
    k_agg                 <<<gagg, 256, 0, stream>>>(g, offs, col, dinv, b_in, act, n);
    // layer 2
    k_gemm<unsigned short><<<ggemm, 512, 0, stream>>>(act, W_hid, dinv, g, n);
    k_agg                 <<<gagg, 256, 0, stream>>>(g, offs, col, dinv, b_hid, act, n);
    // layer 3
    k_gemm<unsigned short><<<ggemm, 512, 0, stream>>>(act, W_hid + CH * CH, dinv, g, n);
    k_agg                 <<<gagg, 256, 0, stream>>>(g, offs, col, dinv, b_hid + CH, act, n);

    // pool + head
    k_pool<<<(n + POOL_CHUNK - 1) / POOL_CHUNK, 128, 0, stream>>>(act, batch, n, sums, cnts);
    k_mlp <<<64, 128, 0, stream>>>(sums, cnts, Wm1, bm1, Wm2, bm2, (float*)d_out);
}

// Round 13
// 906.653 us; speedup vs baseline: 1.2291x; 1.1428x over previous
//
#include <hip/hip_runtime.h>
#include <hip/hip_bf16.h>

// ---------------------------------------------------------------------------
// GCN forward: 3x { g = dinv.(act@W); act' = relu(dinv.(sum g[src] + g) + b) }
//              -> mean-pool(64) -> MLP(5)
// R8 (5th submit; four acquisition timeouts): k_pool rebuilt. R7 post-mortem:
// old k_pool was 143us at 4.2% occupancy (196 blocks, serial 512-row
// scalar-u16 loop per block). New: k_gb finds graph boundaries on the sorted
// batch array (also yields cnts exactly); k_pool = 64 graphs x 8 parts x
// 256 thr, coalesced u32 (2xbf16) loads, 4 rows in flight, LDS row-reduce,
// 128 atomics/block. ~25.6MB stream.
// CSR build (R6/R7 bucket sort with XCD-segmented tails) unchanged.
// ---------------------------------------------------------------------------

#define CH 128
#define BSHIFT 7
#define BW 128            // bucket width = 1<<BSHIFT nodes
#define MAXB 6144         // staged-edge capacity per bucket (avg 4092)
#define HMAX 1024         // max buckets supported
#define NSEG 8            // per-bucket segments (one per XCD group)
#define CPAD 16           // cursor padding (ints) -> one counter per 64B line
#define KB_GRID 2048      // kA_hist and kB_scatter MUST share this grid
#define NGRAPH 64
#define PPART 8           // k_pool parts per graph

static __device__ __forceinline__ unsigned short f2bf(float f) {
    unsigned u = __float_as_uint(f);
    u += 0x7fffu + ((u >> 16) & 1u);          // round-to-nearest-even
    return (unsigned short)(u >> 16);
}
static __device__ __forceinline__ float bf_lo(unsigned u) { return __uint_as_float(u << 16); }
static __device__ __forceinline__ float bf_hi(unsigned u) { return __uint_as_float(u & 0xffff0000u); }

// ---------------- pass A: per-(bucket, group) histogram ----------------
// Same edge->block decomposition as kB_scatter so counts match per (b,g).
__global__ __launch_bounds__(256) void kA_hist(const int* __restrict__ dst, int e,
                                               int* __restrict__ hist, int nb) {
    __shared__ int lh[HMAX];
    for (int i = threadIdx.x; i < nb; i += 256) lh[i] = 0;
    __syncthreads();
    int grp = blockIdx.x & (NSEG - 1);
    int stride = KB_GRID * 256;
    for (int i = blockIdx.x * 256 + threadIdx.x; i < e; i += stride) {
        int d = __builtin_nontemporal_load(&dst[i]);
        atomicAdd(&lh[d >> BSHIFT], 1);
    }
    __syncthreads();
    for (int i = threadIdx.x; i < nb; i += 256) {
        int v = lh[i];
        if (v) atomicAdd(&hist[i * NSEG + grp], v);
    }
}

// ---------------- pass A2: scan (bucket-major, per-seg cursors) -------------
__global__ __launch_bounds__(1024) void kA_scan(const int* __restrict__ hist, int nb,
                                                int* __restrict__ bstart,
                                                int* __restrict__ cursor, int e) {
    __shared__ int sd[1024];
    int t = threadIdx.x;
    int hv[NSEG];
    int v = 0;
    if (t < nb) {
#pragma unroll
        for (int g = 0; g < NSEG; ++g) { hv[g] = hist[t * NSEG + g]; v += hv[g]; }
    }
    sd[t] = v;
    __syncthreads();
    for (int st = 1; st < 1024; st <<= 1) {
        int x = (t >= st) ? sd[t - st] : 0;
        __syncthreads();
        sd[t] += x;
        __syncthreads();
    }
    if (t < nb) {
        int run = sd[t] - v;                  // bucket-exclusive prefix
        bstart[t] = run;
#pragma unroll
        for (int g = 0; g < NSEG; ++g) {
            cursor[(t * NSEG + g) * CPAD] = run;
            run += hv[g];
        }
    }
    if (t == 0) bstart[nb] = e;
}

// ---------------- pass B: scatter edges into per-(bucket,group) segments ----
__global__ __launch_bounds__(256) void kB_scatter(const int* __restrict__ src,
                                                  const int* __restrict__ dst, int e,
                                                  int* __restrict__ cursor,
                                                  unsigned* __restrict__ bdata) {
    int grp = blockIdx.x & (NSEG - 1);
    int stride = KB_GRID * 256;
    for (int i = blockIdx.x * 256 + threadIdx.x; i < e; i += stride) {
        int d = __builtin_nontemporal_load(&dst[i]);
        int s = __builtin_nontemporal_load(&src[i]);
        int b = d >> BSHIFT;
        int pos = atomicAdd(&cursor[(b * NSEG + grp) * CPAD], 1);
        bdata[pos] = ((unsigned)(d & (BW - 1)) << 17) | (unsigned)s;
    }
}

// ---------------- pass C: per-bucket counting sort in LDS ----------------
// Produces: dinv[node], offs[node] (CSR bases), col[] node-grouped src lists.
__global__ __launch_bounds__(256) void kC_bucket(const unsigned* __restrict__ bdata,
                                                 const int* __restrict__ bstart,
                                                 int n, int e,
                                                 int* __restrict__ offs,
                                                 float* __restrict__ dinv,
                                                 int* __restrict__ col) {
    __shared__ int cnt[BW];
    __shared__ int loff[BW];
    __shared__ unsigned est[MAXB];
    __shared__ int lcol[MAXB];
    int b = blockIdx.x, t = threadIdx.x;
    int bbase = bstart[b];
    int m = bstart[b + 1] - bbase;
    int lo = b << BSHIFT;
    bool staged = (m <= MAXB);

    if (t < BW) cnt[t] = 0;
    __syncthreads();
    if (staged) {
        for (int i = t; i < m; i += 256) {
            unsigned u = bdata[bbase + i];
            est[i] = u;
            atomicAdd(&cnt[u >> 17], 1);
        }
    } else {                                  // overflow fallback (never hit at these sizes)
        for (int i = t; i < m; i += 256)
            atomicAdd(&cnt[bdata[bbase + i] >> 17], 1);
    }
    __syncthreads();

    int cv = (t < BW) ? cnt[t] : 0;
    if (t < BW) loff[t] = cv;
    __syncthreads();
    for (int st = 1; st < BW; st <<= 1) {
        int x = 0;
        if (t < BW && t >= st) x = loff[t - st];
        __syncthreads();
        if (t < BW) loff[t] += x;
        __syncthreads();
    }
    if (t < BW) {
        int excl = loff[t] - cv;              // exclusive local offset
        loff[t] = excl;
        int node = lo + t;
        if (node < n) {
            float d = (float)cv + 1.0f;
            dinv[node] = 1.0f / sqrtf(d);
            offs[node] = bbase + excl;
        }
        cnt[t] = 0;                           // reuse as scatter cursor
    }
    if (b == 0 && t == 0) offs[n] = e;
    __syncthreads();

    if (staged) {
        for (int i = t; i < m; i += 256) {
            unsigned u = est[i];
            int ld = u >> 17;
            int pos = atomicAdd(&cnt[ld], 1);
            lcol[loff[ld] + pos] = (int)(u & 0x1FFFFu);
        }
        __syncthreads();
        for (int i = t; i < m; i += 256)      // coalesced flush
            col[bbase + i] = lcol[i];
    } else {
        for (int i = t; i < m; i += 256) {
            unsigned u = bdata[bbase + i];
            int ld = u >> 17;
            int pos = atomicAdd(&cnt[ld], 1);
            col[bbase + loff[ld] + pos] = (int)(u & 0x1FFFFu);
        }
    }
}

// ---------------- GEMM: G[N,128](bf16) = dinv . (A[N,128] @ W[128,128]) -----
// 512 threads, 128 rows/block, W f32 in LDS (64KB -> 2 blocks/CU, 4 w/SIMD).
template <typename TA>
__global__ __launch_bounds__(512) void k_gemm(const TA* __restrict__ A,
                                              const float* __restrict__ W,
                                              const float* __restrict__ dinv,
                                              unsigned short* __restrict__ G, int n) {
    __shared__ float Ws[CH * CH];
    int t = threadIdx.x;
    for (int i = t * 4; i < CH * CH; i += 512 * 4)
        *(float4*)&Ws[i] = *(const float4*)&W[i];
    __syncthreads();

    int rowbase = blockIdx.x * 128;
    int cg = (t & 31) * 4;
    int rg = (t >> 5) * 8;
    float acc[8][4] = {{0.f}};

    for (int k4 = 0; k4 < 32; ++k4) {
        int k = k4 * 4;
        float4 w0 = *(float4*)&Ws[(k + 0) * CH + cg];
        float4 w1 = *(float4*)&Ws[(k + 1) * CH + cg];
        float4 w2 = *(float4*)&Ws[(k + 2) * CH + cg];
        float4 w3 = *(float4*)&Ws[(k + 3) * CH + cg];
#pragma unroll
        for (int j = 0; j < 8; ++j) {
            int row = rowbase + rg + j;
            int rr = row < n ? row : n - 1;           // clamp OOB reads
            float a0, a1, a2, a3;
            if constexpr (sizeof(TA) == 4) {
                float4 xv = *(const float4*)&((const float*)A)[(size_t)rr * CH + k];
                a0 = xv.x; a1 = xv.y; a2 = xv.z; a3 = xv.w;
            } else {
                uint2 uv = *(const uint2*)&((const unsigned short*)A)[(size_t)rr * CH + k];
                a0 = bf_lo(uv.x); a1 = bf_hi(uv.x);
                a2 = bf_lo(uv.y); a3 = bf_hi(uv.y);
            }
            acc[j][0] += a0 * w0.x + a1 * w1.x + a2 * w2.x + a3 * w3.x;
            acc[j][1] += a0 * w0.y + a1 * w1.y + a2 * w2.y + a3 * w3.y;
            acc[j][2] += a0 * w0.z + a1 * w1.z + a2 * w2.z + a3 * w3.z;
            acc[j][3] += a0 * w0.w + a1 * w1.w + a2 * w2.w + a3 * w3.w;
        }
    }
#pragma unroll
    for (int j = 0; j < 8; ++j) {
        int row = rowbase + rg + j;
        if (row < n) {
            float s = dinv[row];
            ushort4 o;
            o.x = f2bf(acc[j][0] * s);
            o.y = f2bf(acc[j][1] * s);
            o.z = f2bf(acc[j][2] * s);
            o.w = f2bf(acc[j][3] * s);
            *(ushort4*)&G[(size_t)row * CH + cg] = o;
        }
    }
}

// ---------------- aggregation: wave per node, lane = 2 bf16 channels --------
// act[i] = relu( dinv[i] * (sum_{src in N(i)} g[src] + g[i]) + b )   (bf16)
__global__ __launch_bounds__(256) void k_agg(const unsigned short* __restrict__ g,
                                             const int* __restrict__ offs,
                                             const int* __restrict__ col,
                                             const float* __restrict__ dinv,
                                             const float* __restrict__ bias,
                                             unsigned short* __restrict__ act, int n) {
    int node = (int)((blockIdx.x * (unsigned)blockDim.x + threadIdx.x) >> 6);
    int lane = threadIdx.x & 63;
    if (node >= n) return;
    int beg = offs[node], end = offs[node + 1];

    const unsigned* gp = (const unsigned*)g;   // one dword = 2 bf16 channels
    float ax = 0.f, ay = 0.f;

    for (int e0 = beg; e0 < end; e0 += 64) {
        int cnt = end - e0; if (cnt > 64) cnt = 64;
        int s_l = (lane < cnt) ? col[e0 + lane] : 0;
        int j = 0;
        for (; j + 4 <= cnt; j += 4) {
            int s0 = __shfl(s_l, j + 0);
            int s1 = __shfl(s_l, j + 1);
            int s2 = __shfl(s_l, j + 2);
            int s3 = __shfl(s_l, j + 3);
            unsigned u0 = gp[(size_t)s0 * 64 + lane];
            unsigned u1 = gp[(size_t)s1 * 64 + lane];
            unsigned u2 = gp[(size_t)s2 * 64 + lane];
            unsigned u3 = gp[(size_t)s3 * 64 + lane];
            ax += bf_lo(u0); ay += bf_hi(u0);
            ax += bf_lo(u1); ay += bf_hi(u1);
            ax += bf_lo(u2); ay += bf_hi(u2);
            ax += bf_lo(u3); ay += bf_hi(u3);
        }
        for (; j < cnt; ++j) {
            int s = __shfl(s_l, j);
            unsigned u = gp[(size_t)s * 64 + lane];
            ax += bf_lo(u); ay += bf_hi(u);
        }
    }

    unsigned us = gp[(size_t)node * 64 + lane];   // self-loop term
    ax += bf_lo(us); ay += bf_hi(us);

    float di = dinv[node];
    float2 b2 = ((const float2*)bias)[lane];
    float ox = fmaxf(ax * di + b2.x, 0.f);
    float oy = fmaxf(ay * di + b2.y, 0.f);
    unsigned o = (unsigned)f2bf(ox) | ((unsigned)f2bf(oy) << 16);
    ((unsigned*)act)[(size_t)node * 64 + lane] = o;
}

// ---------------- graph boundaries on sorted batch -> gstart[65], cnts ------
__global__ __launch_bounds__(256) void k_gb(const int* __restrict__ batch, int n,
                                            int* __restrict__ gstart,
                                            int* __restrict__ cnts) {
    int i = blockIdx.x * 256 + threadIdx.x;
    if (i > n) return;
    if (i == 0) {
        int b0 = batch[0];
        for (int g = 0; g <= b0; ++g) gstart[g] = 0;
    } else if (i == n) {
        int bl = batch[n - 1];
        for (int g = bl + 1; g <= NGRAPH; ++g) gstart[g] = n;
    } else {
        int bp = batch[i - 1], bi = batch[i];
        for (int g = bp + 1; g <= bi; ++g) gstart[g] = i;
    }
    // cnts written by k_pool part 0 (needs completed gstart).
}

// ---------------- pooling: 64 graphs x PPART parts, coalesced u32 loads -----
__global__ __launch_bounds__(256) void k_pool(const unsigned short* __restrict__ act,
                                              const int* __restrict__ gstart,
                                              float* __restrict__ sums,
                                              int* __restrict__ cnts) {
    int g = blockIdx.x >> 3;            // PPART==8
    int part = blockIdx.x & (PPART - 1);
    int beg = gstart[g], end = gstart[g + 1];
    int len = end - beg;
    if (part == 0 && threadIdx.x == 0) cnts[g] = len;
    int pbeg = beg + (int)(((long long)len * part) / PPART);
    int pend = beg + (int)(((long long)len * (part + 1)) / PPART);

    int c2 = threadIdx.x & 63;          // u32 channel pair (ch 2*c2, 2*c2+1)
    int r0 = threadIdx.x >> 6;          // 0..3 row phase
    const unsigned* ap = (const unsigned*)act;
    float ax = 0.f, ay = 0.f;
    for (int i = pbeg + r0; i < pend; i += 4) {
        unsigned u = ap[(size_t)i * 64 + c2];
        ax += bf_lo(u); ay += bf_hi(u);
    }
    __shared__ float red[2][4][64];
    red[0][r0][c2] = ax; red[1][r0][c2] = ay;
    __syncthreads();
    if (r0 == 0) {
        float sx = red[0][0][c2] + red[0][1][c2] + red[0][2][c2] + red[0][3][c2];
        float sy = red[1][0][c2] + red[1][1][c2] + red[1][2][c2] + red[1][3][c2];
        atomicAdd(&sums[g * CH + 2 * c2],     sx);
        atomicAdd(&sums[g * CH + 2 * c2 + 1], sy);
    }
}

// ---------------- MLP head ----------------
__global__ __launch_bounds__(128) void k_mlp(const float* __restrict__ sums,
                                             const int* __restrict__ cnts,
                                             const float* __restrict__ Wm1,
                                             const float* __restrict__ bm1,
                                             const float* __restrict__ Wm2,
                                             const float* __restrict__ bm2,
                                             float* __restrict__ out) {
    int g = blockIdx.x, c = threadIdx.x;
    __shared__ float p[CH];
    __shared__ float hid[CH];
    float invc = 1.0f / fmaxf((float)cnts[g], 1.0f);
    p[c] = sums[g * CH + c] * invc;
    __syncthreads();
    float acc = bm1[c];
    for (int k = 0; k < CH; ++k) acc += p[k] * Wm1[k * CH + c];
    hid[c] = fmaxf(acc, 0.f);
    __syncthreads();
    if (c < 5) {
        float o = bm2[c];
        for (int k = 0; k < CH; ++k) o += hid[k] * Wm2[k * 5 + c];
        out[g * 5 + c] = o;
    }
}

// ---------------------------------------------------------------------------
extern "C" void kernel_launch(void* const* d_in, const int* in_sizes, int n_in,
                              void* d_out, int out_size, void* d_ws, size_t ws_size,
                              hipStream_t stream) {
    const float* x     = (const float*)d_in[0];
    const int*   ei    = (const int*)d_in[1];
    const int*   batch = (const int*)d_in[2];
    const float* W_in  = (const float*)d_in[3];
    const float* b_in  = (const float*)d_in[4];
    const float* W_hid = (const float*)d_in[5];
    const float* b_hid = (const float*)d_in[6];
    const float* Wm1   = (const float*)d_in[7];
    const float* bm1   = (const float*)d_in[8];
    const float* Wm2   = (const float*)d_in[9];
    const float* bm2   = (const float*)d_in[10];

    int n = in_sizes[0] / CH;       // 100000
    int e = in_sizes[1] / 2;        // 3200000
    const int* src = ei;
    const int* dst = ei + e;
    int nb = (n + BW - 1) >> BSHIFT;   // 782 buckets

    // workspace carve (256B aligned)
    char* p = (char*)d_ws;
    auto carve = [&](size_t bytes) {
        void* r = (void*)p;
        p += (bytes + 255) & ~(size_t)255;
        return r;
    };
    unsigned short* g   = (unsigned short*)carve((size_t)n * CH * 2);
    unsigned short* act = (unsigned short*)carve((size_t)n * CH * 2);
    int*   col    = (int*)  carve((size_t)e * 4);
    int*   offs   = (int*)  carve((size_t)(n + 1) * 4);
    float* dinv   = (float*)carve((size_t)n * 4);
    int*   hist   = (int*)  carve((size_t)HMAX * NSEG * 4);
    int*   cursor = (int*)  carve((size_t)HMAX * NSEG * CPAD * 4);
    int*   bstart = (int*)  carve((size_t)(HMAX + 1) * 4);
    float* sums   = (float*)carve(64 * CH * 4);
    int*   cnts   = (int*)  carve(64 * 4);
    int*   gstart = (int*)  carve((NGRAPH + 1) * 4);

    // bdata (e u32 = 12.8MB) aliases act (25.6MB): dead until agg1 writes act.
    unsigned* bdata = (unsigned*)act;

    hipMemsetAsync(hist, 0, (size_t)HMAX * NSEG * 4, stream);
    hipMemsetAsync(sums, 0, 64 * CH * 4, stream);

    kA_hist   <<<KB_GRID, 256, 0, stream>>>(dst, e, hist, nb);
    kA_scan   <<<1, 1024, 0, stream>>>(hist, nb, bstart, cursor, e);
    kB_scatter<<<KB_GRID, 256, 0, stream>>>(src, dst, e, cursor, bdata);
    kC_bucket <<<nb, 256, 0, stream>>>(bdata, bstart, n, e, offs, dinv, col);
    k_gb      <<<(n + 256) / 256, 256, 0, stream>>>(batch, n, gstart, cnts);

    dim3 ggemm((n + 127) / 128);
    dim3 gagg((n + 3) / 4);   // 4 waves per 256-thread block, wave per node

    // layer 1 (f32 input x)
    k_gemm<float>         <<<ggemm, 512, 0, stream>>>(x, W_in, dinv, g, n);
    k_agg                 <<<gagg, 256, 0, stream>>>(g, offs, col, dinv, b_in, act, n);
    // layer 2
    k_gemm<unsigned short><<<ggemm, 512, 0, stream>>>(act, W_hid, dinv, g, n);
    k_agg                 <<<gagg, 256, 0, stream>>>(g, offs, col, dinv, b_hid, act, n);
    // layer 3
    k_gemm<unsigned short><<<ggemm, 512, 0, stream>>>(act, W_hid + CH * CH, dinv, g, n);
    k_agg                 <<<gagg, 256, 0, stream>>>(g, offs, col, dinv, b_hid + CH, act, n);

    // pool + head
    k_pool<<<NGRAPH * PPART, 256, 0, stream>>>(act, gstart, sums, cnts);
    k_mlp <<<NGRAPH, 128, 0, stream>>>(sums, cnts, Wm1, bm1, Wm2, bm2, (float*)d_out);
}

// Round 15
// 888.948 us; speedup vs baseline: 1.2536x; 1.0199x over previous
//
#include <hip/hip_runtime.h>
#include <hip/hip_bf16.h>

// ---------------------------------------------------------------------------
// GCN forward: 3x { g = dinv.(act@W); act' = relu(dinv.(sum g[src] + g) + b) }
//              -> mean-pool(64) -> MLP(5)
// R13 (fix): kA_hist/kB_scatter 8-wide edge batching. kB was 144us at
// 0.9 TB/s (far from BW ceiling), VALUBusy 0.7% -> latency-bound on the
// serial per-edge chain (ntload -> atomicAdd -> store, one in flight).
// Now: 2x 16B nt-loads of dst + 2x of src, 8 independent atomic chains per
// thread -> 8x memory-level parallelism. kA uses the identical edge->block
// mapping so per-(bucket,group) counts still match kB exactly.
// R14 compile fix: __builtin_nontemporal_load requires a clang ext-vector
// type, not HIP's int4 class -> iv4 = int __attribute__((ext_vector_type(4))).
// CSR bucket sort (R6/R7 XCD-segmented tails) + R8 k_pool otherwise unchanged.
// ---------------------------------------------------------------------------

#define CH 128
#define BSHIFT 7
#define BW 128            // bucket width = 1<<BSHIFT nodes
#define MAXB 6144         // staged-edge capacity per bucket (avg 4092)
#define HMAX 1024         // max buckets supported
#define NSEG 8            // per-bucket segments (one per XCD group)
#define CPAD 16           // cursor padding (ints) -> one counter per 64B line
#define KB_GRID 1568      // kA_hist and kB_scatter MUST share this grid;
                          // 1568*256 thr * 8 edges = 3.21M ~= E (1 pack/thread)
#define NGRAPH 64
#define PPART 8           // k_pool parts per graph

typedef int iv4 __attribute__((ext_vector_type(4)));   // nt-loadable 16B int vec

static __device__ __forceinline__ unsigned short f2bf(float f) {
    unsigned u = __float_as_uint(f);
    u += 0x7fffu + ((u >> 16) & 1u);          // round-to-nearest-even
    return (unsigned short)(u >> 16);
}
static __device__ __forceinline__ float bf_lo(unsigned u) { return __uint_as_float(u << 16); }
static __device__ __forceinline__ float bf_hi(unsigned u) { return __uint_as_float(u & 0xffff0000u); }

// ---------------- pass A: per-(bucket, group) histogram, 8-wide -------------
__global__ __launch_bounds__(256) void kA_hist(const int* __restrict__ dst, int e,
                                               int* __restrict__ hist, int nb) {
    __shared__ int lh[HMAX];
    for (int i = threadIdx.x; i < nb; i += 256) lh[i] = 0;
    __syncthreads();
    int grp = blockIdx.x & (NSEG - 1);
    int tid = blockIdx.x * 256 + threadIdx.x;
    int nthr = KB_GRID * 256;
    const iv4* d4 = (const iv4*)dst;
    for (int i = tid * 8; i < e; i += nthr * 8) {
        if (i + 8 <= e) {
            iv4 a = __builtin_nontemporal_load(&d4[i >> 2]);
            iv4 b = __builtin_nontemporal_load(&d4[(i >> 2) + 1]);
            int d[8] = {a.x, a.y, a.z, a.w, b.x, b.y, b.z, b.w};
#pragma unroll
            for (int j = 0; j < 8; ++j) atomicAdd(&lh[d[j] >> BSHIFT], 1);
        } else {
            for (int j = i; j < e; ++j)
                atomicAdd(&lh[__builtin_nontemporal_load(&dst[j]) >> BSHIFT], 1);
        }
    }
    __syncthreads();
    for (int i = threadIdx.x; i < nb; i += 256) {
        int v = lh[i];
        if (v) atomicAdd(&hist[i * NSEG + grp], v);
    }
}

// ---------------- pass A2: scan (bucket-major, per-seg cursors) -------------
__global__ __launch_bounds__(1024) void kA_scan(const int* __restrict__ hist, int nb,
                                                int* __restrict__ bstart,
                                                int* __restrict__ cursor, int e) {
    __shared__ int sd[1024];
    int t = threadIdx.x;
    int hv[NSEG];
    int v = 0;
    if (t < nb) {
#pragma unroll
        for (int g = 0; g < NSEG; ++g) { hv[g] = hist[t * NSEG + g]; v += hv[g]; }
    }
    sd[t] = v;
    __syncthreads();
    for (int st = 1; st < 1024; st <<= 1) {
        int x = (t >= st) ? sd[t - st] : 0;
        __syncthreads();
        sd[t] += x;
        __syncthreads();
    }
    if (t < nb) {
        int run = sd[t] - v;                  // bucket-exclusive prefix
        bstart[t] = run;
#pragma unroll
        for (int g = 0; g < NSEG; ++g) {
            cursor[(t * NSEG + g) * CPAD] = run;
            run += hv[g];
        }
    }
    if (t == 0) bstart[nb] = e;
}

// ---------------- pass B: scatter edges into per-(bucket,group) segments ----
// 8 edges per thread: 4 wide nt-loads, then 8 independent atomic+store chains.
__global__ __launch_bounds__(256) void kB_scatter(const int* __restrict__ src,
                                                  const int* __restrict__ dst, int e,
                                                  int* __restrict__ cursor,
                                                  unsigned* __restrict__ bdata) {
    int grp = blockIdx.x & (NSEG - 1);
    int tid = blockIdx.x * 256 + threadIdx.x;
    int nthr = KB_GRID * 256;
    const iv4* d4 = (const iv4*)dst;
    const iv4* s4 = (const iv4*)src;
    for (int i = tid * 8; i < e; i += nthr * 8) {
        if (i + 8 <= e) {
            iv4 da = __builtin_nontemporal_load(&d4[i >> 2]);
            iv4 db = __builtin_nontemporal_load(&d4[(i >> 2) + 1]);
            iv4 sa = __builtin_nontemporal_load(&s4[i >> 2]);
            iv4 sb = __builtin_nontemporal_load(&s4[(i >> 2) + 1]);
            int d[8] = {da.x, da.y, da.z, da.w, db.x, db.y, db.z, db.w};
            int s[8] = {sa.x, sa.y, sa.z, sa.w, sb.x, sb.y, sb.z, sb.w};
            int pos[8];
#pragma unroll
            for (int j = 0; j < 8; ++j) {
                int b = d[j] >> BSHIFT;
                pos[j] = atomicAdd(&cursor[(b * NSEG + grp) * CPAD], 1);
            }
#pragma unroll
            for (int j = 0; j < 8; ++j)
                bdata[pos[j]] = ((unsigned)(d[j] & (BW - 1)) << 17) | (unsigned)s[j];
        } else {
            for (int j = i; j < e; ++j) {
                int d = __builtin_nontemporal_load(&dst[j]);
                int s = __builtin_nontemporal_load(&src[j]);
                int b = d >> BSHIFT;
                int pos = atomicAdd(&cursor[(b * NSEG + grp) * CPAD], 1);
                bdata[pos] = ((unsigned)(d & (BW - 1)) << 17) | (unsigned)s;
            }
        }
    }
}

// ---------------- pass C: per-bucket counting sort in LDS ----------------
// Produces: dinv[node], offs[node] (CSR bases), col[] node-grouped src lists.
__global__ __launch_bounds__(256) void kC_bucket(const unsigned* __restrict__ bdata,
                                                 const int* __restrict__ bstart,
                                                 int n, int e,
                                                 int* __restrict__ offs,
                                                 float* __restrict__ dinv,
                                                 int* __restrict__ col) {
    __shared__ int cnt[BW];
    __shared__ int loff[BW];
    __shared__ unsigned est[MAXB];
    __shared__ int lcol[MAXB];
    int b = blockIdx.x, t = threadIdx.x;
    int bbase = bstart[b];
    int m = bstart[b + 1] - bbase;
    int lo = b << BSHIFT;
    bool staged = (m <= MAXB);

    if (t < BW) cnt[t] = 0;
    __syncthreads();
    if (staged) {
        for (int i = t; i < m; i += 256) {
            unsigned u = bdata[bbase + i];
            est[i] = u;
            atomicAdd(&cnt[u >> 17], 1);
        }
    } else {                                  // overflow fallback (never hit at these sizes)
        for (int i = t; i < m; i += 256)
            atomicAdd(&cnt[bdata[bbase + i] >> 17], 1);
    }
    __syncthreads();

    int cv = (t < BW) ? cnt[t] : 0;
    if (t < BW) loff[t] = cv;
    __syncthreads();
    for (int st = 1; st < BW; st <<= 1) {
        int x = 0;
        if (t < BW && t >= st) x = loff[t - st];
        __syncthreads();
        if (t < BW) loff[t] += x;
        __syncthreads();
    }
    if (t < BW) {
        int excl = loff[t] - cv;              // exclusive local offset
        loff[t] = excl;
        int node = lo + t;
        if (node < n) {
            float d = (float)cv + 1.0f;
            dinv[node] = 1.0f / sqrtf(d);
            offs[node] = bbase + excl;
        }
        cnt[t] = 0;                           // reuse as scatter cursor
    }
    if (b == 0 && t == 0) offs[n] = e;
    __syncthreads();

    if (staged) {
        for (int i = t; i < m; i += 256) {
            unsigned u = est[i];
            int ld = u >> 17;
            int pos = atomicAdd(&cnt[ld], 1);
            lcol[loff[ld] + pos] = (int)(u & 0x1FFFFu);
        }
        __syncthreads();
        for (int i = t; i < m; i += 256)      // coalesced flush
            col[bbase + i] = lcol[i];
    } else {
        for (int i = t; i < m; i += 256) {
            unsigned u = bdata[bbase + i];
            int ld = u >> 17;
            int pos = atomicAdd(&cnt[ld], 1);
            col[bbase + loff[ld] + pos] = (int)(u & 0x1FFFFu);
        }
    }
}

// ---------------- GEMM: G[N,128](bf16) = dinv . (A[N,128] @ W[128,128]) -----
// 512 threads, 128 rows/block, W f32 in LDS (64KB -> 2 blocks/CU, 4 w/SIMD).
template <typename TA>
__global__ __launch_bounds__(512) void k_gemm(const TA* __restrict__ A,
                                              const float* __restrict__ W,
                                              const float* __restrict__ dinv,
                                              unsigned short* __restrict__ G, int n) {
    __shared__ float Ws[CH * CH];
    int t = threadIdx.x;
    for (int i = t * 4; i < CH * CH; i += 512 * 4)
        *(float4*)&Ws[i] = *(const float4*)&W[i];
    __syncthreads();

    int rowbase = blockIdx.x * 128;
    int cg = (t & 31) * 4;
    int rg = (t >> 5) * 8;
    float acc[8][4] = {{0.f}};

    for (int k4 = 0; k4 < 32; ++k4) {
        int k = k4 * 4;
        float4 w0 = *(float4*)&Ws[(k + 0) * CH + cg];
        float4 w1 = *(float4*)&Ws[(k + 1) * CH + cg];
        float4 w2 = *(float4*)&Ws[(k + 2) * CH + cg];
        float4 w3 = *(float4*)&Ws[(k + 3) * CH + cg];
#pragma unroll
        for (int j = 0; j < 8; ++j) {
            int row = rowbase + rg + j;
            int rr = row < n ? row : n - 1;           // clamp OOB reads
            float a0, a1, a2, a3;
            if constexpr (sizeof(TA) == 4) {
                float4 xv = *(const float4*)&((const float*)A)[(size_t)rr * CH + k];
                a0 = xv.x; a1 = xv.y; a2 = xv.z; a3 = xv.w;
            } else {
                uint2 uv = *(const uint2*)&((const unsigned short*)A)[(size_t)rr * CH + k];
                a0 = bf_lo(uv.x); a1 = bf_hi(uv.x);
                a2 = bf_lo(uv.y); a3 = bf_hi(uv.y);
            }
            acc[j][0] += a0 * w0.x + a1 * w1.x + a2 * w2.x + a3 * w3.x;
            acc[j][1] += a0 * w0.y + a1 * w1.y + a2 * w2.y + a3 * w3.y;
            acc[j][2] += a0 * w0.z + a1 * w1.z + a2 * w2.z + a3 * w3.z;
            acc[j][3] += a0 * w0.w + a1 * w1.w + a2 * w2.w + a3 * w3.w;
        }
    }
#pragma unroll
    for (int j = 0; j < 8; ++j) {
        int row = rowbase + rg + j;
        if (row < n) {
            float s = dinv[row];
            ushort4 o;
            o.x = f2bf(acc[j][0] * s);
            o.y = f2bf(acc[j][1] * s);
            o.z = f2bf(acc[j][2] * s);
            o.w = f2bf(acc[j][3] * s);
            *(ushort4*)&G[(size_t)row * CH + cg] = o;
        }
    }
}

// ---------------- aggregation: wave per node, lane = 2 bf16 channels --------
// act[i] = relu( dinv[i] * (sum_{src in N(i)} g[src] + g[i]) + b )   (bf16)
__global__ __launch_bounds__(256) void k_agg(const unsigned short* __restrict__ g,
                                             const int* __restrict__ offs,
                                             const int* __restrict__ col,
                                             const float* __restrict__ dinv,
                                             const float* __restrict__ bias,
                                             unsigned short* __restrict__ act, int n) {
    int node = (int)((blockIdx.x * (unsigned)blockDim.x + threadIdx.x) >> 6);
    int lane = threadIdx.x & 63;
    if (node >= n) return;
    int beg = offs[node], end = offs[node + 1];

    const unsigned* gp = (const unsigned*)g;   // one dword = 2 bf16 channels
    float ax = 0.f, ay = 0.f;

    for (int e0 = beg; e0 < end; e0 += 64) {
        int cnt = end - e0; if (cnt > 64) cnt = 64;
        int s_l = (lane < cnt) ? col[e0 + lane] : 0;
        int j = 0;
        for (; j + 4 <= cnt; j += 4) {
            int s0 = __shfl(s_l, j + 0);
            int s1 = __shfl(s_l, j + 1);
            int s2 = __shfl(s_l, j + 2);
            int s3 = __shfl(s_l, j + 3);
            unsigned u0 = gp[(size_t)s0 * 64 + lane];
            unsigned u1 = gp[(size_t)s1 * 64 + lane];
            unsigned u2 = gp[(size_t)s2 * 64 + lane];
            unsigned u3 = gp[(size_t)s3 * 64 + lane];
            ax += bf_lo(u0); ay += bf_hi(u0);
            ax += bf_lo(u1); ay += bf_hi(u1);
            ax += bf_lo(u2); ay += bf_hi(u2);
            ax += bf_lo(u3); ay += bf_hi(u3);
        }
        for (; j < cnt; ++j) {
            int s = __shfl(s_l, j);
            unsigned u = gp[(size_t)s * 64 + lane];
            ax += bf_lo(u); ay += bf_hi(u);
        }
    }

    unsigned us = gp[(size_t)node * 64 + lane];   // self-loop term
    ax += bf_lo(us); ay += bf_hi(us);

    float di = dinv[node];
    float2 b2 = ((const float2*)bias)[lane];
    float ox = fmaxf(ax * di + b2.x, 0.f);
    float oy = fmaxf(ay * di + b2.y, 0.f);
    unsigned o = (unsigned)f2bf(ox) | ((unsigned)f2bf(oy) << 16);
    ((unsigned*)act)[(size_t)node * 64 + lane] = o;
}

// ---------------- graph boundaries on sorted batch -> gstart[65], cnts ------
__global__ __launch_bounds__(256) void k_gb(const int* __restrict__ batch, int n,
                                            int* __restrict__ gstart,
                                            int* __restrict__ cnts) {
    int i = blockIdx.x * 256 + threadIdx.x;
    if (i > n) return;
    if (i == 0) {
        int b0 = batch[0];
        for (int g = 0; g <= b0; ++g) gstart[g] = 0;
    } else if (i == n) {
        int bl = batch[n - 1];
        for (int g = bl + 1; g <= NGRAPH; ++g) gstart[g] = n;
    } else {
        int bp = batch[i - 1], bi = batch[i];
        for (int g = bp + 1; g <= bi; ++g) gstart[g] = i;
    }
    // cnts written by k_pool part 0 (needs completed gstart).
}

// ---------------- pooling: 64 graphs x PPART parts, coalesced u32 loads -----
__global__ __launch_bounds__(256) void k_pool(const unsigned short* __restrict__ act,
                                              const int* __restrict__ gstart,
                                              float* __restrict__ sums,
                                              int* __restrict__ cnts) {
    int g = blockIdx.x >> 3;            // PPART==8
    int part = blockIdx.x & (PPART - 1);
    int beg = gstart[g], end = gstart[g + 1];
    int len = end - beg;
    if (part == 0 && threadIdx.x == 0) cnts[g] = len;
    int pbeg = beg + (int)(((long long)len * part) / PPART);
    int pend = beg + (int)(((long long)len * (part + 1)) / PPART);

    int c2 = threadIdx.x & 63;          // u32 channel pair (ch 2*c2, 2*c2+1)
    int r0 = threadIdx.x >> 6;          // 0..3 row phase
    const unsigned* ap = (const unsigned*)act;
    float ax = 0.f, ay = 0.f;
    for (int i = pbeg + r0; i < pend; i += 4) {
        unsigned u = ap[(size_t)i * 64 + c2];
        ax += bf_lo(u); ay += bf_hi(u);
    }
    __shared__ float red[2][4][64];
    red[0][r0][c2] = ax; red[1][r0][c2] = ay;
    __syncthreads();
    if (r0 == 0) {
        float sx = red[0][0][c2] + red[0][1][c2] + red[0][2][c2] + red[0][3][c2];
        float sy = red[1][0][c2] + red[1][1][c2] + red[1][2][c2] + red[1][3][c2];
        atomicAdd(&sums[g * CH + 2 * c2],     sx);
        atomicAdd(&sums[g * CH + 2 * c2 + 1], sy);
    }
}

// ---------------- MLP head ----------------
__global__ __launch_bounds__(128) void k_mlp(const float* __restrict__ sums,
                                             const int* __restrict__ cnts,
                                             const float* __restrict__ Wm1,
                                             const float* __restrict__ bm1,
                                             const float* __restrict__ Wm2,
                                             const float* __restrict__ bm2,
                                             float* __restrict__ out) {
    int g = blockIdx.x, c = threadIdx.x;
    __shared__ float p[CH];
    __shared__ float hid[CH];
    float invc = 1.0f / fmaxf((float)cnts[g], 1.0f);
    p[c] = sums[g * CH + c] * invc;
    __syncthreads();
    float acc = bm1[c];
    for (int k = 0; k < CH; ++k) acc += p[k] * Wm1[k * CH + c];
    hid[c] = fmaxf(acc, 0.f);
    __syncthreads();
    if (c < 5) {
        float o = bm2[c];
        for (int k = 0; k < CH; ++k) o += hid[k] * Wm2[k * 5 + c];
        out[g * 5 + c] = o;
    }
}

// ---------------------------------------------------------------------------
extern "C" void kernel_launch(void* const* d_in, const int* in_sizes, int n_in,
                              void* d_out, int out_size, void* d_ws, size_t ws_size,
                              hipStream_t stream) {
    const float* x     = (const float*)d_in[0];
    const int*   ei    = (const int*)d_in[1];
    const int*   batch = (const int*)d_in[2];
    const float* W_in  = (const float*)d_in[3];
    const float* b_in  = (const float*)d_in[4];
    const float* W_hid = (const float*)d_in[5];
    const float* b_hid = (const float*)d_in[6];
    const float* Wm1   = (const float*)d_in[7];
    const float* bm1   = (const float*)d_in[8];
    const float* Wm2   = (const float*)d_in[9];
    const float* bm2   = (const float*)d_in[10];

    int n = in_sizes[0] / CH;       // 100000
    int e = in_sizes[1] / 2;        // 3200000
    const int* src = ei;
    const int* dst = ei + e;
    int nb = (n + BW - 1) >> BSHIFT;   // 782 buckets

    // workspace carve (256B aligned)
    char* p = (char*)d_ws;
    auto carve = [&](size_t bytes) {
        void* r = (void*)p;
        p += (bytes + 255) & ~(size_t)255;
        return r;
    };
    unsigned short* g   = (unsigned short*)carve((size_t)n * CH * 2);
    unsigned short* act = (unsigned short*)carve((size_t)n * CH * 2);
    int*   col    = (int*)  carve((size_t)e * 4);
    int*   offs   = (int*)  carve((size_t)(n + 1) * 4);
    float* dinv   = (float*)carve((size_t)n * 4);
    int*   hist   = (int*)  carve((size_t)HMAX * NSEG * 4);
    int*   cursor = (int*)  carve((size_t)HMAX * NSEG * CPAD * 4);
    int*   bstart = (int*)  carve((size_t)(HMAX + 1) * 4);
    float* sums   = (float*)carve(64 * CH * 4);
    int*   cnts   = (int*)  carve(64 * 4);
    int*   gstart = (int*)  carve((NGRAPH + 1) * 4);

    // bdata (e u32 = 12.8MB) aliases act (25.6MB): dead until agg1 writes act.
    unsigned* bdata = (unsigned*)act;

    hipMemsetAsync(hist, 0, (size_t)HMAX * NSEG * 4, stream);
    hipMemsetAsync(sums, 0, 64 * CH * 4, stream);

    kA_hist   <<<KB_GRID, 256, 0, stream>>>(dst, e, hist, nb);
    kA_scan   <<<1, 1024, 0, stream>>>(hist, nb, bstart, cursor, e);
    kB_scatter<<<KB_GRID, 256, 0, stream>>>(src, dst, e, cursor, bdata);
    kC_bucket <<<nb, 256, 0, stream>>>(bdata, bstart, n, e, offs, dinv, col);
    k_gb      <<<(n + 256) / 256, 256, 0, stream>>>(batch, n, gstart, cnts);

    dim3 ggemm((n + 127) / 128);
    dim3 gagg((n + 3) / 4);   // 4 waves per 256-thread block, wave per node

    // layer 1 (f32 input x)
    k_gemm<float>         <<<ggemm, 512, 0, stream>>>(x, W_in, dinv, g, n);
    k_agg                 <<<gagg, 256, 0, stream>>>(g, offs, col, dinv, b_in, act, n);
    // layer 2
    k_gemm<unsigned short><<<ggemm, 512, 0, stream>>>(act, W_hid, dinv, g, n);
    k_agg                 <<<gagg, 256, 0, stream>>>(g, offs, col, dinv, b_hid, act, n);
    // layer 3
    k_gemm<unsigned short><<<ggemm, 512, 0, stream>>>(act, W_hid + CH * CH, dinv, g, n);
    k_agg                 <<<gagg, 256, 0, stream>>>(g, offs, col, dinv, b_hid + CH, act, n);

    // pool + head
    k_pool<<<NGRAPH * PPART, 256, 0, stream>>>(act, gstart, sums, cnts);
    k_mlp <<<NGRAPH, 128, 0, stream>>>(sums, cnts, Wm1, bm1, Wm2, bm2, (float*)d_out);
}